// Round 20
// baseline (208.238 us; speedup 1.0000x reference)
//
#include <hip/hip_runtime.h>

#define BSZ 256
#define NND 22
#define BN_EPS 1e-5f

typedef float v2f __attribute__((ext_vector_type(2)));

__device__ __forceinline__ v2f pkfma(v2f a, v2f b, v2f c) {
  return __builtin_elementwise_fma(a, b, c);
}

// ---------------------------------------------------------------------------
// conv core for CIN<=4 (used by S1 only). c-loop unroll-1 ON PURPOSE.
// ---------------------------------------------------------------------------
template<int CIN, int COUT, int R, int SROW>
__device__ __forceinline__ void conv_coreR(
    const float (*s_in)[SROW], const float* s_w, int tid, float y[COUT][R]) {
#pragma unroll
  for (int o = 0; o < COUT; o++)
#pragma unroll
    for (int r = 0; r < R; r++) y[o][r] = 0.f;
#pragma unroll 1
  for (int c = 0; c < CIN; c++) {
    float xr[R + 6];
    const float4* xp = (const float4*)&s_in[c][4 * tid];
    float4 xa = xp[0], xb = xp[1];
    float2 xc = *(const float2*)&s_in[c][4 * tid + 8];
    xr[0] = xa.x; xr[1] = xa.y; xr[2] = xa.z; xr[3] = xa.w;
    xr[4] = xb.x; xr[5] = xb.y; xr[6] = xb.z; xr[7] = xb.w;
    xr[8] = xc.x; xr[9] = xc.y;
#pragma unroll
    for (int k = 0; k < 7; k++) {
      const float4* wp = (const float4*)&s_w[(c * 7 + k) * COUT];
#pragma unroll
      for (int o4 = 0; o4 < COUT / 4; o4++) {
        float4 wv = wp[o4];
#pragma unroll
        for (int r = 0; r < R; r++) {
          y[4 * o4 + 0][r] += wv.x * xr[r + k];
          y[4 * o4 + 1][r] += wv.y * xr[r + k];
          y[4 * o4 + 2][r] += wv.z * xr[r + k];
          y[4 * o4 + 3][r] += wv.w * xr[r + k];
        }
      }
    }
  }
}

template<int CIN, int COUT, int NTH>
__device__ __forceinline__ void stage_weights(const float* __restrict__ w,
                                              float* s_w, int tid) {
  for (int i = tid; i < CIN * 7 * COUT; i += NTH) {
    int c = i / (7 * COUT), k = (i / COUT) % 7, o = i % COUT;
    s_w[i] = w[(o * CIN + c) * 7 + k];
  }
}

// ---------------------------------------------------------------------------
// S1': conv1 stats -> partial slot, AND pooled raw conv1 -> y1p[n][b][4][1000]
// (pool commutes with BN1, scale1>0). grid: (2, BSZ, NND), block 256.
// ---------------------------------------------------------------------------
template<int CIN, int COUT, int LIN, int NTH, int NT, int R>
__global__ __launch_bounds__(NTH) void conv_stats1p(
    const float* __restrict__ in, long sn, long sb, long sc,
    const float* __restrict__ w, float* __restrict__ part,
    float* __restrict__ y1p) {
  const int TILE = R * NTH;
  const int SROW = TILE + 8;
  __shared__ alignas(16) float s_in[CIN][SROW];
  __shared__ alignas(16) float s_w[CIN * 7 * COUT];
  __shared__ float s_red[2][NTH / 64][COUT];
  int tid = threadIdx.x, n = blockIdx.z, b = blockIdx.y;
  int t0 = blockIdx.x * TILE;
  const float* base = in + (long)n * sn + (long)b * sb;
  stage_weights<CIN, COUT, NTH>(w, s_w, tid);
  for (int c = 0; c < CIN; c++)
    for (int i = tid; i < TILE + 6; i += NTH) {
      int l = t0 + i - 3;
      s_in[c][i] = (l >= 0 && l < LIN) ? base[(long)c * sc + l] : 0.f;
    }
  __syncthreads();
  float y[COUT][R];
  conv_coreR<CIN, COUT, R, SROW>(s_in, s_w, tid, y);
  bool valid = (t0 + R * tid) < LIN;
  if (valid) {
    int p0 = (t0 + R * tid) >> 1;
    long yb = ((long)n * BSZ + b) * 4000 + p0;
#pragma unroll
    for (int o = 0; o < COUT; o++) {
      float2 v;
      v.x = fmaxf(y[o][0], y[o][1]);
      v.y = fmaxf(y[o][2], y[o][3]);
      *(float2*)&y1p[yb + (long)o * 1000] = v;
    }
  }
  int lane = tid & 63, wv = tid >> 6;
#pragma unroll
  for (int o = 0; o < COUT; o++) {
    float s = 0.f, q = 0.f;
    if (valid) {
#pragma unroll
      for (int r = 0; r < R; r++) { s += y[o][r]; q += y[o][r] * y[o][r]; }
    }
#pragma unroll
    for (int off = 32; off > 0; off >>= 1) {
      s += __shfl_down(s, off, 64);
      q += __shfl_down(q, off, 64);
    }
    if (lane == 0) { s_red[0][wv][o] = s; s_red[1][wv][o] = q; }
  }
  __syncthreads();
  if (tid < COUT) {
    float s = 0.f, q = 0.f;
#pragma unroll
    for (int g = 0; g < NTH / 64; g++) { s += s_red[0][g][tid]; q += s_red[1][g][tid]; }
    long slot = ((long)n * NT + blockIdx.x) * BSZ + b;
    part[slot * (2 * COUT) + tid] = s;
    part[slot * (2 * COUT) + COUT + tid] = q;
  }
}

// ---------------------------------------------------------------------------
// Reduce partials -> BN scale/shift. Block 0 (w2t!=nullptr) also transposes
// conv2/conv3 weights to [c][k][o].
// ---------------------------------------------------------------------------
template<int C, int NSLOT, int LIN>
__global__ __launch_bounds__(256) void stats_reduce(
    const float* __restrict__ part,
    const float* __restrict__ gamma, const float* __restrict__ beta,
    float* __restrict__ scs,
    const float* __restrict__ w2, const float* __restrict__ w3,
    float* __restrict__ w2t, float* __restrict__ w3t) {
  const int V = 2 * C;
  const int GRP = 256 / V;
  int n = blockIdx.x, tid = threadIdx.x;
  int j = tid % V, g = tid / V;
  const float* p = part + (long)n * NSLOT * V;
  float s = 0.f;
  for (int sl = g; sl < NSLOT; sl += GRP) s += p[(long)sl * V + j];
  __shared__ float red[V][GRP];
  __shared__ float tot[V];
  red[j][g] = s;
  __syncthreads();
  if (tid < V) {
    float t = 0.f;
#pragma unroll
    for (int gg = 0; gg < GRP; gg++) t += red[tid][gg];
    tot[tid] = t;
  }
  __syncthreads();
  if (tid < C) {
    float cnt = (float)BSZ * (float)LIN;
    float m = tot[tid] / cnt;
    float var = tot[C + tid] / cnt - m * m;
    float istd = 1.0f / sqrtf(var + BN_EPS);
    float scl = gamma[tid] * istd;
    scs[n * 64 + tid] = scl;
    scs[n * 64 + 32 + tid] = beta[tid] - m * scl;
  }
  if (w2t != nullptr && blockIdx.x == 0) {
    if (tid < 224) {
      int c = tid / 56, k = (tid / 8) % 7, o = tid & 7;
      w2t[tid] = w2[(o * 4 + c) * 7 + k];
    }
    for (int i = tid; i < 896; i += 256) {
      int c = i / 112, k = (i / 16) % 7, o = i & 15;
      w3t[i] = w3[(o * 8 + c) * 7 + k];
    }
  }
}

// ---------------------------------------------------------------------------
// F1: conv2 direct-from-global over y1p, DEPTH-2 prefetch (even/odd named
// register sets; loads issued 2 c-iterations ahead to cover ~900cy latency
// vs the 224-FMA/448cy compute window — the R19 post-mortem's exposed-stall
// fix). BN1+ReLU in regs; weights via uniform s_load.
// grid: (1, B, N), block 256 (250 active).
// ---------------------------------------------------------------------------
__global__ __launch_bounds__(256) void fused1(
    const float* __restrict__ y1p,    // [n][b][4][1000] pooled raw conv1
    const float* __restrict__ scs1,
    const float* __restrict__ w2t,    // [c][k][o] transposed conv2 weights
    float* __restrict__ y2p,          // [n][b][8][500] pooled raw conv2
    float* __restrict__ p2) {         // [(n*256+b)*16]
  __shared__ float s_red[2][4][8];
  int tid = threadIdx.x, n = blockIdx.z, b = blockIdx.y;
  bool valid = tid < 250;                           // 4*250 = 1000 exactly
  v2f y2v[4][4];
#pragma unroll
  for (int oo = 0; oo < 4; oo++)
#pragma unroll
    for (int r = 0; r < 4; r++) { y2v[oo][r].x = 0.f; y2v[oo][r].y = 0.f; }
  if (valid) {
    const float* yrow = y1p + ((long)n * BSZ + b) * 4000;
    bool p0 = (tid == 0), pE = (tid == 249);
    int offA = p0 ? 0 : 4 * tid - 4;
    int offB = 4 * tid;                             // <= 996
    int offC = pE ? 996 : 4 * tid + 4;
    // depth-2 prologue: rows 0 (even) and 1 (odd)
    float4 eA = *(const float4*)&yrow[offA];
    float4 eB = *(const float4*)&yrow[offB];
    float4 eC = *(const float4*)&yrow[offC];
    float4 oA = *(const float4*)&yrow[1000 + offA];
    float4 oB = *(const float4*)&yrow[1000 + offB];
    float4 oC = *(const float4*)&yrow[1000 + offC];
#pragma unroll 1
    for (int cc = 0; cc < 2; cc++) {
      int c0 = 2 * cc, c1 = 2 * cc + 1;
      // ---- even step: consume c0, prefetch c0+2 (rows 2..4; 4 = in-ws garbage)
      {
        float4 A = eA, B = eB, C = eC;
        const float* nxt = yrow + (c0 + 2) * 1000;
        eA = *(const float4*)&nxt[offA];
        eB = *(const float4*)&nxt[offB];
        eC = *(const float4*)&nxt[offC];
        float sc = scs1[n * 64 + c0], sh = scs1[n * 64 + 32 + c0];
        float xr[12];
        xr[0] = A.x; xr[1] = A.y; xr[2] = A.z; xr[3] = A.w;
        xr[4] = B.x; xr[5] = B.y; xr[6] = B.z; xr[7] = B.w;
        xr[8] = C.x; xr[9] = C.y; xr[10] = C.z; xr[11] = C.w;
#pragma unroll
        for (int j = 0; j < 12; j++) xr[j] = fmaxf(xr[j] * sc + sh, 0.f);
        if (p0) { xr[1] = 0.f; xr[2] = 0.f; xr[3] = 0.f; }
        if (pE) { xr[8] = 0.f; xr[9] = 0.f; xr[10] = 0.f; }
#pragma unroll
        for (int k = 0; k < 7; k++) {
          float4 w0 = *(const float4*)&w2t[(c0 * 7 + k) * 8];
          float4 w1v = *(const float4*)&w2t[(c0 * 7 + k) * 8 + 4];
          v2f wp0, wp1, wp2, wp3;
          wp0.x = w0.x; wp0.y = w0.y;
          wp1.x = w0.z; wp1.y = w0.w;
          wp2.x = w1v.x; wp2.y = w1v.y;
          wp3.x = w1v.z; wp3.y = w1v.w;
#pragma unroll
          for (int r = 0; r < 4; r++) {
            v2f xs; xs.x = xr[r + k + 1]; xs.y = xr[r + k + 1];
            y2v[0][r] = pkfma(wp0, xs, y2v[0][r]);
            y2v[1][r] = pkfma(wp1, xs, y2v[1][r]);
            y2v[2][r] = pkfma(wp2, xs, y2v[2][r]);
            y2v[3][r] = pkfma(wp3, xs, y2v[3][r]);
          }
        }
      }
      // ---- odd step: consume c1, prefetch c1+2 (rows 3..5; 4,5 garbage)
      {
        float4 A = oA, B = oB, C = oC;
        const float* nxt = yrow + (c1 + 2) * 1000;
        oA = *(const float4*)&nxt[offA];
        oB = *(const float4*)&nxt[offB];
        oC = *(const float4*)&nxt[offC];
        float sc = scs1[n * 64 + c1], sh = scs1[n * 64 + 32 + c1];
        float xr[12];
        xr[0] = A.x; xr[1] = A.y; xr[2] = A.z; xr[3] = A.w;
        xr[4] = B.x; xr[5] = B.y; xr[6] = B.z; xr[7] = B.w;
        xr[8] = C.x; xr[9] = C.y; xr[10] = C.z; xr[11] = C.w;
#pragma unroll
        for (int j = 0; j < 12; j++) xr[j] = fmaxf(xr[j] * sc + sh, 0.f);
        if (p0) { xr[1] = 0.f; xr[2] = 0.f; xr[3] = 0.f; }
        if (pE) { xr[8] = 0.f; xr[9] = 0.f; xr[10] = 0.f; }
#pragma unroll
        for (int k = 0; k < 7; k++) {
          float4 w0 = *(const float4*)&w2t[(c1 * 7 + k) * 8];
          float4 w1v = *(const float4*)&w2t[(c1 * 7 + k) * 8 + 4];
          v2f wp0, wp1, wp2, wp3;
          wp0.x = w0.x; wp0.y = w0.y;
          wp1.x = w0.z; wp1.y = w0.w;
          wp2.x = w1v.x; wp2.y = w1v.y;
          wp3.x = w1v.z; wp3.y = w1v.w;
#pragma unroll
          for (int r = 0; r < 4; r++) {
            v2f xs; xs.x = xr[r + k + 1]; xs.y = xr[r + k + 1];
            y2v[0][r] = pkfma(wp0, xs, y2v[0][r]);
            y2v[1][r] = pkfma(wp1, xs, y2v[1][r]);
            y2v[2][r] = pkfma(wp2, xs, y2v[2][r]);
            y2v[3][r] = pkfma(wp3, xs, y2v[3][r]);
          }
        }
      }
    }
    long yb = ((long)n * BSZ + b) * 4000 + 2 * tid;
#pragma unroll
    for (int oo = 0; oo < 4; oo++) {
      float2 vx, vy;
      vx.x = fmaxf(y2v[oo][0].x, y2v[oo][1].x);
      vx.y = fmaxf(y2v[oo][2].x, y2v[oo][3].x);
      *(float2*)&y2p[yb + (2 * oo) * 500] = vx;
      vy.x = fmaxf(y2v[oo][0].y, y2v[oo][1].y);
      vy.y = fmaxf(y2v[oo][2].y, y2v[oo][3].y);
      *(float2*)&y2p[yb + (2 * oo + 1) * 500] = vy;
    }
  }
  int lane = tid & 63, wv = tid >> 6;
#pragma unroll
  for (int o = 0; o < 8; o++) {
    float g0 = (o & 1) ? y2v[o >> 1][0].y : y2v[o >> 1][0].x;
    float g1 = (o & 1) ? y2v[o >> 1][1].y : y2v[o >> 1][1].x;
    float g2 = (o & 1) ? y2v[o >> 1][2].y : y2v[o >> 1][2].x;
    float g3 = (o & 1) ? y2v[o >> 1][3].y : y2v[o >> 1][3].x;
    float s = g0 + g1 + g2 + g3;
    float q = g0 * g0 + g1 * g1 + g2 * g2 + g3 * g3;
#pragma unroll
    for (int off = 32; off > 0; off >>= 1) {
      s += __shfl_down(s, off, 64);
      q += __shfl_down(q, off, 64);
    }
    if (lane == 0) { s_red[0][wv][o] = s; s_red[1][wv][o] = q; }
  }
  __syncthreads();
  if (tid < 8) {
    float s = 0.f, q = 0.f;
#pragma unroll
    for (int g = 0; g < 4; g++) { s += s_red[0][g][tid]; q += s_red[1][g][tid]; }
    long slot = (long)n * BSZ + b;
    p2[slot * 16 + tid] = s;
    p2[slot * 16 + 8 + tid] = q;
  }
}

// ---------------------------------------------------------------------------
// F2: conv3 direct-from-global, all 16 channels/thread, DEPTH-2 prefetch
// (even/odd named sets, 2 c-iterations ahead). grid: (1, B, N), block 128.
// ---------------------------------------------------------------------------
__global__ __launch_bounds__(128) void fused2(
    const float* __restrict__ y2p,    // [n][b][8][500]
    const float* __restrict__ scs2,
    const float* __restrict__ w3t,    // [c][k][o] transposed conv3 weights
    float* __restrict__ y3p,          // [n][b][16][250] pooled raw conv3
    float* __restrict__ p3) {         // [(n*256+b)*32]
  __shared__ float s_red[2][2][16];
  int tid = threadIdx.x, n = blockIdx.z, b = blockIdx.y;
  bool valid = tid < 125;                           // 4*125 = 500 exactly
  v2f acc[8][4];
#pragma unroll
  for (int oo = 0; oo < 8; oo++)
#pragma unroll
    for (int r = 0; r < 4; r++) { acc[oo][r].x = 0.f; acc[oo][r].y = 0.f; }
  if (valid) {
    const float* yrow = y2p + ((long)n * BSZ + b) * 4000;
    bool p0 = (tid == 0), pE = (tid == 124);
    int offA = p0 ? 0 : 4 * tid - 4;
    int offB = 4 * tid;                             // <= 496
    int offC = pE ? 496 : 4 * tid + 4;
    // depth-2 prologue: rows 0 (even) and 1 (odd)
    float4 eA = *(const float4*)&yrow[offA];
    float4 eB = *(const float4*)&yrow[offB];
    float4 eC = *(const float4*)&yrow[offC];
    float4 oA = *(const float4*)&yrow[500 + offA];
    float4 oB = *(const float4*)&yrow[500 + offB];
    float4 oC = *(const float4*)&yrow[500 + offC];
#pragma unroll 1
    for (int cc = 0; cc < 4; cc++) {
      int c0 = 2 * cc, c1 = 2 * cc + 1;
      // ---- even step: consume c0, prefetch c0+2 (rows 2..8; 8 garbage)
      {
        float4 A = eA, B = eB, C = eC;
        const float* nxt = yrow + (c0 + 2) * 500;
        eA = *(const float4*)&nxt[offA];
        eB = *(const float4*)&nxt[offB];
        eC = *(const float4*)&nxt[offC];
        float sc = scs2[n * 64 + c0], sh = scs2[n * 64 + 32 + c0];
        float xr[12];
        xr[0] = A.x; xr[1] = A.y; xr[2] = A.z; xr[3] = A.w;
        xr[4] = B.x; xr[5] = B.y; xr[6] = B.z; xr[7] = B.w;
        xr[8] = C.x; xr[9] = C.y; xr[10] = C.z; xr[11] = C.w;
#pragma unroll
        for (int j = 0; j < 12; j++) xr[j] = fmaxf(xr[j] * sc + sh, 0.f);
        if (p0) { xr[1] = 0.f; xr[2] = 0.f; xr[3] = 0.f; }
        if (pE) { xr[8] = 0.f; xr[9] = 0.f; xr[10] = 0.f; }
#pragma unroll
        for (int k = 0; k < 7; k++) {
          const float* wb = &w3t[(c0 * 7 + k) * 16];
          float4 w0 = *(const float4*)&wb[0];
          float4 w1v = *(const float4*)&wb[4];
          float4 w2v = *(const float4*)&wb[8];
          float4 w3v = *(const float4*)&wb[12];
          v2f wp0, wp1, wp2, wp3, wp4, wp5, wp6, wp7;
          wp0.x = w0.x; wp0.y = w0.y;   wp1.x = w0.z; wp1.y = w0.w;
          wp2.x = w1v.x; wp2.y = w1v.y; wp3.x = w1v.z; wp3.y = w1v.w;
          wp4.x = w2v.x; wp4.y = w2v.y; wp5.x = w2v.z; wp5.y = w2v.w;
          wp6.x = w3v.x; wp6.y = w3v.y; wp7.x = w3v.z; wp7.y = w3v.w;
#pragma unroll
          for (int r = 0; r < 4; r++) {
            v2f xs; xs.x = xr[r + k + 1]; xs.y = xr[r + k + 1];
            acc[0][r] = pkfma(wp0, xs, acc[0][r]);
            acc[1][r] = pkfma(wp1, xs, acc[1][r]);
            acc[2][r] = pkfma(wp2, xs, acc[2][r]);
            acc[3][r] = pkfma(wp3, xs, acc[3][r]);
            acc[4][r] = pkfma(wp4, xs, acc[4][r]);
            acc[5][r] = pkfma(wp5, xs, acc[5][r]);
            acc[6][r] = pkfma(wp6, xs, acc[6][r]);
            acc[7][r] = pkfma(wp7, xs, acc[7][r]);
          }
        }
      }
      // ---- odd step: consume c1, prefetch c1+2 (rows 3..9; 8,9 garbage)
      {
        float4 A = oA, B = oB, C = oC;
        const float* nxt = yrow + (c1 + 2) * 500;
        oA = *(const float4*)&nxt[offA];
        oB = *(const float4*)&nxt[offB];
        oC = *(const float4*)&nxt[offC];
        float sc = scs2[n * 64 + c1], sh = scs2[n * 64 + 32 + c1];
        float xr[12];
        xr[0] = A.x; xr[1] = A.y; xr[2] = A.z; xr[3] = A.w;
        xr[4] = B.x; xr[5] = B.y; xr[6] = B.z; xr[7] = B.w;
        xr[8] = C.x; xr[9] = C.y; xr[10] = C.z; xr[11] = C.w;
#pragma unroll
        for (int j = 0; j < 12; j++) xr[j] = fmaxf(xr[j] * sc + sh, 0.f);
        if (p0) { xr[1] = 0.f; xr[2] = 0.f; xr[3] = 0.f; }
        if (pE) { xr[8] = 0.f; xr[9] = 0.f; xr[10] = 0.f; }
#pragma unroll
        for (int k = 0; k < 7; k++) {
          const float* wb = &w3t[(c1 * 7 + k) * 16];
          float4 w0 = *(const float4*)&wb[0];
          float4 w1v = *(const float4*)&wb[4];
          float4 w2v = *(const float4*)&wb[8];
          float4 w3v = *(const float4*)&wb[12];
          v2f wp0, wp1, wp2, wp3, wp4, wp5, wp6, wp7;
          wp0.x = w0.x; wp0.y = w0.y;   wp1.x = w0.z; wp1.y = w0.w;
          wp2.x = w1v.x; wp2.y = w1v.y; wp3.x = w1v.z; wp3.y = w1v.w;
          wp4.x = w2v.x; wp4.y = w2v.y; wp5.x = w2v.z; wp5.y = w2v.w;
          wp6.x = w3v.x; wp6.y = w3v.y; wp7.x = w3v.z; wp7.y = w3v.w;
#pragma unroll
          for (int r = 0; r < 4; r++) {
            v2f xs; xs.x = xr[r + k + 1]; xs.y = xr[r + k + 1];
            acc[0][r] = pkfma(wp0, xs, acc[0][r]);
            acc[1][r] = pkfma(wp1, xs, acc[1][r]);
            acc[2][r] = pkfma(wp2, xs, acc[2][r]);
            acc[3][r] = pkfma(wp3, xs, acc[3][r]);
            acc[4][r] = pkfma(wp4, xs, acc[4][r]);
            acc[5][r] = pkfma(wp5, xs, acc[5][r]);
            acc[6][r] = pkfma(wp6, xs, acc[6][r]);
            acc[7][r] = pkfma(wp7, xs, acc[7][r]);
          }
        }
      }
    }
    long yb = ((long)n * BSZ + b) * 4000 + 2 * tid; // 16*250 = 4000
#pragma unroll
    for (int oo = 0; oo < 8; oo++) {
      float2 vx, vy;
      vx.x = fmaxf(acc[oo][0].x, acc[oo][1].x);
      vx.y = fmaxf(acc[oo][2].x, acc[oo][3].x);
      *(float2*)&y3p[yb + (2 * oo) * 250] = vx;
      vy.x = fmaxf(acc[oo][0].y, acc[oo][1].y);
      vy.y = fmaxf(acc[oo][2].y, acc[oo][3].y);
      *(float2*)&y3p[yb + (2 * oo + 1) * 250] = vy;
    }
  }
  int lane = tid & 63, wv = tid >> 6;
#pragma unroll
  for (int o = 0; o < 16; o++) {
    float g0 = (o & 1) ? acc[o >> 1][0].y : acc[o >> 1][0].x;
    float g1 = (o & 1) ? acc[o >> 1][1].y : acc[o >> 1][1].x;
    float g2 = (o & 1) ? acc[o >> 1][2].y : acc[o >> 1][2].x;
    float g3 = (o & 1) ? acc[o >> 1][3].y : acc[o >> 1][3].x;
    float s = g0 + g1 + g2 + g3;
    float q = g0 * g0 + g1 * g1 + g2 * g2 + g3 * g3;
#pragma unroll
    for (int off = 32; off > 0; off >>= 1) {
      s += __shfl_down(s, off, 64);
      q += __shfl_down(q, off, 64);
    }
    if (lane == 0) { s_red[0][wv][o] = s; s_red[1][wv][o] = q; }
  }
  __syncthreads();
  if (tid < 16) {
    float s = s_red[0][0][tid] + s_red[0][1][tid];
    float q = s_red[1][0][tid] + s_red[1][1][tid];
    long slot = (long)n * BSZ + b;
    p3[slot * 32 + tid] = s;
    p3[slot * 32 + 16 + tid] = q;
  }
}

// ---------------------------------------------------------------------------
// F3: BN3 + ReLU + avg over pooled raw conv3 -> feat[b][n][16].
// grid: (1, B, N), block 256 (16 chans x 16 threads).
// ---------------------------------------------------------------------------
__global__ __launch_bounds__(256) void feat_apply(
    const float* __restrict__ y3p,
    const float* __restrict__ scs3,
    float* __restrict__ feat) {
  int tid = threadIdx.x, n = blockIdx.z, b = blockIdx.y;
  int ch = tid >> 4, s = tid & 15;
  const float* yb = y3p + (((long)n * BSZ + b) * 16 + ch) * 250;
  float sc = scs3[n * 64 + ch], sh = scs3[n * 64 + 32 + ch];
  float acc = 0.f;
  for (int j = s; j < 125; j += 16) {
    float2 v = *(const float2*)&yb[2 * j];
    acc += fmaxf(v.x * sc + sh, 0.f) + fmaxf(v.y * sc + sh, 0.f);
  }
#pragma unroll
  for (int off = 8; off > 0; off >>= 1) acc += __shfl_down(acc, off, 16);
  if (s == 0) feat[((long)b * NND + n) * 16 + ch] = acc * (1.0f / 250.f);
}

// ---------------------------------------------------------------------------
// Graph tail: adjacency (top-4 incl self) + 3 GCN layers + node-mean + MLP
// grid: (B), block: 256.
// ---------------------------------------------------------------------------
__global__ __launch_bounds__(256) void graph_head(
    const float* __restrict__ feat,
    const float* __restrict__ gw1, const float* __restrict__ gb1,
    const float* __restrict__ gw2, const float* __restrict__ gb2,
    const float* __restrict__ gw3, const float* __restrict__ gb3,
    const float* __restrict__ fw1, const float* __restrict__ fb1,
    const float* __restrict__ fw2, const float* __restrict__ fb2,
    float* __restrict__ out) {
  int b = blockIdx.x, tid = threadIdx.x;
  __shared__ float s_feat[NND][16];
  __shared__ float s_sq[NND];
  __shared__ float s_dist[NND][NND];
  __shared__ float s_adj[NND][NND];
  __shared__ float s_x[NND][128];
  __shared__ float s_t[NND][128];
  __shared__ float s_pool[128];
  __shared__ float s_h[64];
  for (int i = tid; i < NND * 16; i += 256) s_feat[i >> 4][i & 15] = feat[b * NND * 16 + i];
  __syncthreads();
  if (tid < NND) {
    float s = 0.f;
    for (int c = 0; c < 16; c++) s += s_feat[tid][c] * s_feat[tid][c];
    s_sq[tid] = s;
  }
  __syncthreads();
  for (int i = tid; i < NND * NND; i += 256) {
    int nn = i / NND, m = i % NND;
    float d = 0.f;
    for (int c = 0; c < 16; c++) d += s_feat[nn][c] * s_feat[m][c];
    s_dist[nn][m] = s_sq[nn] + s_sq[m] - 2.f * d;  // diagonal exactly 0
    s_adj[nn][m] = 0.f;
  }
  __syncthreads();
  if (tid < NND) {  // top-4 smallest, ties -> earliest index (matches top_k)
    unsigned used = 0;
    for (int j = 0; j < 4; j++) {
      float best = 3.4e38f; int bi = 0;
      for (int m = 0; m < NND; m++)
        if (!((used >> m) & 1u) && s_dist[tid][m] < best) { best = s_dist[tid][m]; bi = m; }
      used |= 1u << bi;
      s_adj[tid][bi] = 0.25f;
    }
  }
  __syncthreads();
  for (int i = tid; i < NND * 32; i += 256) {
    int nn = i / 32, f = i % 32;
    float a = 0.f;
    for (int c = 0; c < 16; c++) a += s_feat[nn][c] * gw1[c * 32 + f];
    s_t[nn][f] = a;
  }
  __syncthreads();
  for (int i = tid; i < NND * 32; i += 256) {
    int nn = i / 32, f = i % 32;
    float a = gb1[f];
    for (int m = 0; m < NND; m++) a += s_adj[nn][m] * s_t[m][f];
    s_x[nn][f] = fmaxf(a, 0.f);
  }
  __syncthreads();
  for (int i = tid; i < NND * 64; i += 256) {
    int nn = i / 64, f = i % 64;
    float a = 0.f;
    for (int c = 0; c < 32; c++) a += s_x[nn][c] * gw2[c * 64 + f];
    s_t[nn][f] = a;
  }
  __syncthreads();
  for (int i = tid; i < NND * 64; i += 256) {
    int nn = i / 64, f = i % 64;
    float a = gb2[f];
    for (int m = 0; m < NND; m++) a += s_adj[nn][m] * s_t[m][f];
    s_x[nn][f] = fmaxf(a, 0.f);
  }
  __syncthreads();
  for (int i = tid; i < NND * 128; i += 256) {
    int nn = i / 128, f = i % 128;
    float a = 0.f;
    for (int c = 0; c < 64; c++) a += s_x[nn][c] * gw3[c * 128 + f];
    s_t[nn][f] = a;
  }
  __syncthreads();
  for (int i = tid; i < NND * 128; i += 256) {
    int nn = i / 128, f = i % 128;
    float a = gb3[f];
    for (int m = 0; m < NND; m++) a += s_adj[nn][m] * s_t[m][f];
    s_x[nn][f] = fmaxf(a, 0.f);
  }
  __syncthreads();
  if (tid < 128) {
    float a = 0.f;
    for (int m = 0; m < NND; m++) a += s_x[m][tid];
    s_pool[tid] = a * (1.0f / (float)NND);
  }
  __syncthreads();
  if (tid < 64) {
    float a = fb1[tid];
    for (int c = 0; c < 128; c++) a += s_pool[c] * fw1[c * 64 + tid];
    s_h[tid] = a;
  }
  __syncthreads();
  if (tid < 4) {
    float a = fb2[tid];
    for (int c = 0; c < 64; c++) a += s_h[c] * fw2[c * 4 + tid];
    out[b * 4 + tid] = a;
  }
}

extern "C" void kernel_launch(void* const* d_in, const int* in_sizes, int n_in,
                              void* d_out, int out_size, void* d_ws, size_t ws_size,
                              hipStream_t stream) {
  (void)in_sizes; (void)n_in; (void)out_size; (void)ws_size;
  const float* x   = (const float*)d_in[0];
  const float* w1  = (const float*)d_in[1];
  const float* g1  = (const float*)d_in[2];
  const float* b1  = (const float*)d_in[3];
  const float* w2  = (const float*)d_in[4];
  const float* g2  = (const float*)d_in[5];
  const float* b2  = (const float*)d_in[6];
  const float* w3  = (const float*)d_in[7];
  const float* g3  = (const float*)d_in[8];
  const float* b3  = (const float*)d_in[9];
  const float* gw1 = (const float*)d_in[10];
  const float* gb1 = (const float*)d_in[11];
  const float* gw2 = (const float*)d_in[12];
  const float* gb2 = (const float*)d_in[13];
  const float* gw3 = (const float*)d_in[14];
  const float* gb3 = (const float*)d_in[15];
  const float* fw1 = (const float*)d_in[16];
  const float* fb1 = (const float*)d_in[17];
  const float* fw2 = (const float*)d_in[18];
  const float* fb2 = (const float*)d_in[19];

  float* ws = (float*)d_ws;
  const long RSZ = (long)NND * BSZ * 4000;      // 22,528,000 floats per region
  float* y1p  = ws;                              // region A (reused as y3p)
  float* y3p  = ws;                              //   y1p dead before fused2 writes
  float* y2p  = ws + RSZ;                        // region B
  float* feat = y2p + RSZ;                       // B*N*16 = 90,112
  float* scs1 = feat + (long)BSZ * NND * 16;
  float* scs2 = scs1 + NND * 64;
  float* scs3 = scs2 + NND * 64;
  float* p1   = scs3 + NND * 64;                 // 22*512 slots * 8
  float* p2   = p1 + (long)NND * 512 * 8;        // 22*256 slots * 16
  float* p3   = p2 + (long)NND * 256 * 16;       // 22*256 slots * 32
  float* w2t  = p3 + (long)NND * 256 * 32;       // 224
  float* w3t  = w2t + 224;                       // 896
  // total ws ~= 181 MB (same budget as all prior passing rounds)

  // S1': conv1 stats + pooled raw conv1 -> y1p
  conv_stats1p<1, 4, 2000, 256, 2, 4><<<dim3(2, BSZ, NND), dim3(256), 0, stream>>>(
      x, 2000, (long)NND * 2000, 0, w1, p1, y1p);
  // reduce1 (+ weight pre-transpose in block 0)
  stats_reduce<4, 512, 2000><<<dim3(NND), dim3(256), 0, stream>>>(
      p1, g1, b1, scs1, w2, w3, w2t, w3t);
  // conv2 direct-from-global, depth-2 prefetch -> y2p + stats2
  fused1<<<dim3(1, BSZ, NND), dim3(256), 0, stream>>>(y1p, scs1, w2t, y2p, p2);
  stats_reduce<8, 256, 1000><<<dim3(NND), dim3(256), 0, stream>>>(
      p2, g2, b2, scs2, nullptr, nullptr, nullptr, nullptr);
  // conv3 direct-from-global, 16 chan/thread, depth-2 prefetch -> y3p + stats3
  fused2<<<dim3(1, BSZ, NND), dim3(128), 0, stream>>>(y2p, scs2, w3t, y3p, p3);
  stats_reduce<16, 256, 500><<<dim3(NND), dim3(256), 0, stream>>>(
      p3, g3, b3, scs3, nullptr, nullptr, nullptr, nullptr);
  // BN3 + ReLU + avg -> feat
  feat_apply<<<dim3(1, BSZ, NND), dim3(256), 0, stream>>>(y3p, scs3, feat);
  // graph tail
  graph_head<<<dim3(BSZ), dim3(256), 0, stream>>>(
      feat, gw1, gb1, gw2, gb2, gw3, gb3, fw1, fb1, fw2, fb2, (float*)d_out);
}

// Round 21
// 199.440 us; speedup vs baseline: 1.0441x; 1.0441x over previous
//
#include <hip/hip_runtime.h>

#define BSZ 256
#define NND 22
#define BN_EPS 1e-5f

typedef float v2f __attribute__((ext_vector_type(2)));

__device__ __forceinline__ v2f pkfma(v2f a, v2f b, v2f c) {
  return __builtin_elementwise_fma(a, b, c);
}

// ---------------------------------------------------------------------------
// conv core for CIN<=4 (used by S1 only). c-loop unroll-1 ON PURPOSE.
// ---------------------------------------------------------------------------
template<int CIN, int COUT, int R, int SROW>
__device__ __forceinline__ void conv_coreR(
    const float (*s_in)[SROW], const float* s_w, int tid, float y[COUT][R]) {
#pragma unroll
  for (int o = 0; o < COUT; o++)
#pragma unroll
    for (int r = 0; r < R; r++) y[o][r] = 0.f;
#pragma unroll 1
  for (int c = 0; c < CIN; c++) {
    float xr[R + 6];
    const float4* xp = (const float4*)&s_in[c][4 * tid];
    float4 xa = xp[0], xb = xp[1];
    float2 xc = *(const float2*)&s_in[c][4 * tid + 8];
    xr[0] = xa.x; xr[1] = xa.y; xr[2] = xa.z; xr[3] = xa.w;
    xr[4] = xb.x; xr[5] = xb.y; xr[6] = xb.z; xr[7] = xb.w;
    xr[8] = xc.x; xr[9] = xc.y;
#pragma unroll
    for (int k = 0; k < 7; k++) {
      const float4* wp = (const float4*)&s_w[(c * 7 + k) * COUT];
#pragma unroll
      for (int o4 = 0; o4 < COUT / 4; o4++) {
        float4 wv = wp[o4];
#pragma unroll
        for (int r = 0; r < R; r++) {
          y[4 * o4 + 0][r] += wv.x * xr[r + k];
          y[4 * o4 + 1][r] += wv.y * xr[r + k];
          y[4 * o4 + 2][r] += wv.z * xr[r + k];
          y[4 * o4 + 3][r] += wv.w * xr[r + k];
        }
      }
    }
  }
}

template<int CIN, int COUT, int NTH>
__device__ __forceinline__ void stage_weights(const float* __restrict__ w,
                                              float* s_w, int tid) {
  for (int i = tid; i < CIN * 7 * COUT; i += NTH) {
    int c = i / (7 * COUT), k = (i / COUT) % 7, o = i % COUT;
    s_w[i] = w[(o * CIN + c) * 7 + k];
  }
}

// ---------------------------------------------------------------------------
// S1': conv1 stats -> partial slot, AND pooled raw conv1 -> y1p[n][b][4][1000]
// (pool commutes with BN1, scale1>0). grid: (2, BSZ, NND), block 256.
// ---------------------------------------------------------------------------
template<int CIN, int COUT, int LIN, int NTH, int NT, int R>
__global__ __launch_bounds__(NTH) void conv_stats1p(
    const float* __restrict__ in, long sn, long sb, long sc,
    const float* __restrict__ w, float* __restrict__ part,
    float* __restrict__ y1p) {
  const int TILE = R * NTH;
  const int SROW = TILE + 8;
  __shared__ alignas(16) float s_in[CIN][SROW];
  __shared__ alignas(16) float s_w[CIN * 7 * COUT];
  __shared__ float s_red[2][NTH / 64][COUT];
  int tid = threadIdx.x, n = blockIdx.z, b = blockIdx.y;
  int t0 = blockIdx.x * TILE;
  const float* base = in + (long)n * sn + (long)b * sb;
  stage_weights<CIN, COUT, NTH>(w, s_w, tid);
  for (int c = 0; c < CIN; c++)
    for (int i = tid; i < TILE + 6; i += NTH) {
      int l = t0 + i - 3;
      s_in[c][i] = (l >= 0 && l < LIN) ? base[(long)c * sc + l] : 0.f;
    }
  __syncthreads();
  float y[COUT][R];
  conv_coreR<CIN, COUT, R, SROW>(s_in, s_w, tid, y);
  bool valid = (t0 + R * tid) < LIN;
  if (valid) {
    int p0 = (t0 + R * tid) >> 1;
    long yb = ((long)n * BSZ + b) * 4000 + p0;
#pragma unroll
    for (int o = 0; o < COUT; o++) {
      float2 v;
      v.x = fmaxf(y[o][0], y[o][1]);
      v.y = fmaxf(y[o][2], y[o][3]);
      *(float2*)&y1p[yb + (long)o * 1000] = v;
    }
  }
  int lane = tid & 63, wv = tid >> 6;
#pragma unroll
  for (int o = 0; o < COUT; o++) {
    float s = 0.f, q = 0.f;
    if (valid) {
#pragma unroll
      for (int r = 0; r < R; r++) { s += y[o][r]; q += y[o][r] * y[o][r]; }
    }
#pragma unroll
    for (int off = 32; off > 0; off >>= 1) {
      s += __shfl_down(s, off, 64);
      q += __shfl_down(q, off, 64);
    }
    if (lane == 0) { s_red[0][wv][o] = s; s_red[1][wv][o] = q; }
  }
  __syncthreads();
  if (tid < COUT) {
    float s = 0.f, q = 0.f;
#pragma unroll
    for (int g = 0; g < NTH / 64; g++) { s += s_red[0][g][tid]; q += s_red[1][g][tid]; }
    long slot = ((long)n * NT + blockIdx.x) * BSZ + b;
    part[slot * (2 * COUT) + tid] = s;
    part[slot * (2 * COUT) + COUT + tid] = q;
  }
}

// ---------------------------------------------------------------------------
// Reduce partials -> BN scale/shift. Block 0 (w2t!=nullptr) also transposes
// conv2/conv3 weights to [c][k][o].
// ---------------------------------------------------------------------------
template<int C, int NSLOT, int LIN>
__global__ __launch_bounds__(256) void stats_reduce(
    const float* __restrict__ part,
    const float* __restrict__ gamma, const float* __restrict__ beta,
    float* __restrict__ scs,
    const float* __restrict__ w2, const float* __restrict__ w3,
    float* __restrict__ w2t, float* __restrict__ w3t) {
  const int V = 2 * C;
  const int GRP = 256 / V;
  int n = blockIdx.x, tid = threadIdx.x;
  int j = tid % V, g = tid / V;
  const float* p = part + (long)n * NSLOT * V;
  float s = 0.f;
  for (int sl = g; sl < NSLOT; sl += GRP) s += p[(long)sl * V + j];
  __shared__ float red[V][GRP];
  __shared__ float tot[V];
  red[j][g] = s;
  __syncthreads();
  if (tid < V) {
    float t = 0.f;
#pragma unroll
    for (int gg = 0; gg < GRP; gg++) t += red[tid][gg];
    tot[tid] = t;
  }
  __syncthreads();
  if (tid < C) {
    float cnt = (float)BSZ * (float)LIN;
    float m = tot[tid] / cnt;
    float var = tot[C + tid] / cnt - m * m;
    float istd = 1.0f / sqrtf(var + BN_EPS);
    float scl = gamma[tid] * istd;
    scs[n * 64 + tid] = scl;
    scs[n * 64 + 32 + tid] = beta[tid] - m * scl;
  }
  if (w2t != nullptr && blockIdx.x == 0) {
    if (tid < 224) {
      int c = tid / 56, k = (tid / 8) % 7, o = tid & 7;
      w2t[tid] = w2[(o * 4 + c) * 7 + k];
    }
    for (int i = tid; i < 896; i += 256) {
      int c = i / 112, k = (i / 16) % 7, o = i & 15;
      w3t[i] = w3[(o * 8 + c) * 7 + k];
    }
  }
}

// ---------------------------------------------------------------------------
// F1: conv2 direct-from-global over y1p (BN1+ReLU in regs), weights via
// uniform global s_load. -> pooled raw conv2 (y2p) + stats2 partials.
// grid: (1, B, N), block 256 (250 active).
// ---------------------------------------------------------------------------
__global__ __launch_bounds__(256) void fused1(
    const float* __restrict__ y1p,    // [n][b][4][1000] pooled raw conv1
    const float* __restrict__ scs1,
    const float* __restrict__ w2t,    // [c][k][o] transposed conv2 weights
    float* __restrict__ y2p,          // [n][b][8][500] pooled raw conv2
    float* __restrict__ p2) {         // [(n*256+b)*16]
  __shared__ float s_red[2][4][8];
  int tid = threadIdx.x, n = blockIdx.z, b = blockIdx.y;
  bool valid = tid < 250;                           // 4*250 = 1000 exactly
  v2f y2v[4][4];
#pragma unroll
  for (int oo = 0; oo < 4; oo++)
#pragma unroll
    for (int r = 0; r < 4; r++) { y2v[oo][r].x = 0.f; y2v[oo][r].y = 0.f; }
  if (valid) {
    const float* yrow = y1p + ((long)n * BSZ + b) * 4000;
    bool p0 = (tid == 0), pE = (tid == 249);
    int offA = p0 ? 0 : 4 * tid - 4;
    int offB = 4 * tid;                             // <= 996
    int offC = pE ? 996 : 4 * tid + 4;
    float4 nA = *(const float4*)&yrow[offA];
    float4 nB = *(const float4*)&yrow[offB];
    float4 nC = *(const float4*)&yrow[offC];
#pragma unroll 1
    for (int c = 0; c < 4; c++) {
      float4 A = nA, B = nB, C = nC;
      const float* nxt = yrow + (c + 1) * 1000;     // c=3 prefetch: in-ws garbage
      nA = *(const float4*)&nxt[offA];
      nB = *(const float4*)&nxt[offB];
      nC = *(const float4*)&nxt[offC];
      float sc = scs1[n * 64 + c], sh = scs1[n * 64 + 32 + c];  // uniform s_load
      float xr[12];
      xr[0] = A.x; xr[1] = A.y; xr[2] = A.z; xr[3] = A.w;
      xr[4] = B.x; xr[5] = B.y; xr[6] = B.z; xr[7] = B.w;
      xr[8] = C.x; xr[9] = C.y; xr[10] = C.z; xr[11] = C.w;
#pragma unroll
      for (int j = 0; j < 12; j++) xr[j] = fmaxf(xr[j] * sc + sh, 0.f);  // BN1+ReLU
      if (p0) { xr[1] = 0.f; xr[2] = 0.f; xr[3] = 0.f; }
      if (pE) { xr[8] = 0.f; xr[9] = 0.f; xr[10] = 0.f; }
#pragma unroll
      for (int k = 0; k < 7; k++) {
        float4 w0 = *(const float4*)&w2t[(c * 7 + k) * 8];       // s_load
        float4 w1v = *(const float4*)&w2t[(c * 7 + k) * 8 + 4];
        v2f wp0, wp1, wp2, wp3;
        wp0.x = w0.x; wp0.y = w0.y;
        wp1.x = w0.z; wp1.y = w0.w;
        wp2.x = w1v.x; wp2.y = w1v.y;
        wp3.x = w1v.z; wp3.y = w1v.w;
#pragma unroll
        for (int r = 0; r < 4; r++) {
          v2f xs; xs.x = xr[r + k + 1]; xs.y = xr[r + k + 1];
          y2v[0][r] = pkfma(wp0, xs, y2v[0][r]);
          y2v[1][r] = pkfma(wp1, xs, y2v[1][r]);
          y2v[2][r] = pkfma(wp2, xs, y2v[2][r]);
          y2v[3][r] = pkfma(wp3, xs, y2v[3][r]);
        }
      }
    }
    long yb = ((long)n * BSZ + b) * 4000 + 2 * tid;
#pragma unroll
    for (int oo = 0; oo < 4; oo++) {
      float2 vx, vy;
      vx.x = fmaxf(y2v[oo][0].x, y2v[oo][1].x);
      vx.y = fmaxf(y2v[oo][2].x, y2v[oo][3].x);
      *(float2*)&y2p[yb + (2 * oo) * 500] = vx;
      vy.x = fmaxf(y2v[oo][0].y, y2v[oo][1].y);
      vy.y = fmaxf(y2v[oo][2].y, y2v[oo][3].y);
      *(float2*)&y2p[yb + (2 * oo + 1) * 500] = vy;
    }
  }
  int lane = tid & 63, wv = tid >> 6;
#pragma unroll
  for (int o = 0; o < 8; o++) {
    float g0 = (o & 1) ? y2v[o >> 1][0].y : y2v[o >> 1][0].x;
    float g1 = (o & 1) ? y2v[o >> 1][1].y : y2v[o >> 1][1].x;
    float g2 = (o & 1) ? y2v[o >> 1][2].y : y2v[o >> 1][2].x;
    float g3 = (o & 1) ? y2v[o >> 1][3].y : y2v[o >> 1][3].x;
    float s = g0 + g1 + g2 + g3;
    float q = g0 * g0 + g1 * g1 + g2 * g2 + g3 * g3;
#pragma unroll
    for (int off = 32; off > 0; off >>= 1) {
      s += __shfl_down(s, off, 64);
      q += __shfl_down(q, off, 64);
    }
    if (lane == 0) { s_red[0][wv][o] = s; s_red[1][wv][o] = q; }
  }
  __syncthreads();
  if (tid < 8) {
    float s = 0.f, q = 0.f;
#pragma unroll
    for (int g = 0; g < 4; g++) { s += s_red[0][g][tid]; q += s_red[1][g][tid]; }
    long slot = (long)n * BSZ + b;
    p2[slot * 16 + tid] = s;
    p2[slot * 16 + 8 + tid] = q;
  }
}

// ---------------------------------------------------------------------------
// F2: conv3 direct-from-global, ALL 16 CHANNELS PER THREAD (best-measured
// config, R19: 125 active threads of 128, 4 positions each, depth-1
// prefetch, weights via uniform s_load). grid: (1, B, N), block 128.
// ---------------------------------------------------------------------------
__global__ __launch_bounds__(128) void fused2(
    const float* __restrict__ y2p,    // [n][b][8][500]
    const float* __restrict__ scs2,
    const float* __restrict__ w3t,    // [c][k][o] transposed conv3 weights
    float* __restrict__ y3p,          // [n][b][16][250] pooled raw conv3
    float* __restrict__ p3) {         // [(n*256+b)*32]
  __shared__ float s_red[2][2][16];
  int tid = threadIdx.x, n = blockIdx.z, b = blockIdx.y;
  bool valid = tid < 125;                           // 4*125 = 500 exactly
  v2f acc[8][4];
#pragma unroll
  for (int oo = 0; oo < 8; oo++)
#pragma unroll
    for (int r = 0; r < 4; r++) { acc[oo][r].x = 0.f; acc[oo][r].y = 0.f; }
  if (valid) {
    const float* yrow = y2p + ((long)n * BSZ + b) * 4000;
    bool p0 = (tid == 0), pE = (tid == 124);
    int offA = p0 ? 0 : 4 * tid - 4;
    int offB = 4 * tid;                             // <= 496
    int offC = pE ? 496 : 4 * tid + 4;
    float4 nA = *(const float4*)&yrow[offA];
    float4 nB = *(const float4*)&yrow[offB];
    float4 nC = *(const float4*)&yrow[offC];
#pragma unroll 1
    for (int c = 0; c < 8; c++) {
      float4 A = nA, B = nB, C = nC;
      const float* nxt = yrow + (c + 1) * 500;      // c=7 prefetch: in-ws garbage
      nA = *(const float4*)&nxt[offA];
      nB = *(const float4*)&nxt[offB];
      nC = *(const float4*)&nxt[offC];
      float sc = scs2[n * 64 + c], sh = scs2[n * 64 + 32 + c];  // uniform s_load
      float xr[12];
      xr[0] = A.x; xr[1] = A.y; xr[2] = A.z; xr[3] = A.w;
      xr[4] = B.x; xr[5] = B.y; xr[6] = B.z; xr[7] = B.w;
      xr[8] = C.x; xr[9] = C.y; xr[10] = C.z; xr[11] = C.w;
#pragma unroll
      for (int j = 0; j < 12; j++) xr[j] = fmaxf(xr[j] * sc + sh, 0.f);  // BN2+ReLU
      if (p0) { xr[1] = 0.f; xr[2] = 0.f; xr[3] = 0.f; }
      if (pE) { xr[8] = 0.f; xr[9] = 0.f; xr[10] = 0.f; }
#pragma unroll
      for (int k = 0; k < 7; k++) {
        const float* wb = &w3t[(c * 7 + k) * 16];
        float4 w0 = *(const float4*)&wb[0];          // uniform -> s_load x4
        float4 w1v = *(const float4*)&wb[4];
        float4 w2v = *(const float4*)&wb[8];
        float4 w3v = *(const float4*)&wb[12];
        v2f wp0, wp1, wp2, wp3, wp4, wp5, wp6, wp7;
        wp0.x = w0.x; wp0.y = w0.y;   wp1.x = w0.z; wp1.y = w0.w;
        wp2.x = w1v.x; wp2.y = w1v.y; wp3.x = w1v.z; wp3.y = w1v.w;
        wp4.x = w2v.x; wp4.y = w2v.y; wp5.x = w2v.z; wp5.y = w2v.w;
        wp6.x = w3v.x; wp6.y = w3v.y; wp7.x = w3v.z; wp7.y = w3v.w;
#pragma unroll
        for (int r = 0; r < 4; r++) {
          v2f xs; xs.x = xr[r + k + 1]; xs.y = xr[r + k + 1];
          acc[0][r] = pkfma(wp0, xs, acc[0][r]);
          acc[1][r] = pkfma(wp1, xs, acc[1][r]);
          acc[2][r] = pkfma(wp2, xs, acc[2][r]);
          acc[3][r] = pkfma(wp3, xs, acc[3][r]);
          acc[4][r] = pkfma(wp4, xs, acc[4][r]);
          acc[5][r] = pkfma(wp5, xs, acc[5][r]);
          acc[6][r] = pkfma(wp6, xs, acc[6][r]);
          acc[7][r] = pkfma(wp7, xs, acc[7][r]);
        }
      }
    }
    long yb = ((long)n * BSZ + b) * 4000 + 2 * tid; // 16*250 = 4000
#pragma unroll
    for (int oo = 0; oo < 8; oo++) {
      float2 vx, vy;
      vx.x = fmaxf(acc[oo][0].x, acc[oo][1].x);
      vx.y = fmaxf(acc[oo][2].x, acc[oo][3].x);
      *(float2*)&y3p[yb + (2 * oo) * 250] = vx;
      vy.x = fmaxf(acc[oo][0].y, acc[oo][1].y);
      vy.y = fmaxf(acc[oo][2].y, acc[oo][3].y);
      *(float2*)&y3p[yb + (2 * oo + 1) * 250] = vy;
    }
  }
  int lane = tid & 63, wv = tid >> 6;
#pragma unroll
  for (int o = 0; o < 16; o++) {
    float g0 = (o & 1) ? acc[o >> 1][0].y : acc[o >> 1][0].x;
    float g1 = (o & 1) ? acc[o >> 1][1].y : acc[o >> 1][1].x;
    float g2 = (o & 1) ? acc[o >> 1][2].y : acc[o >> 1][2].x;
    float g3 = (o & 1) ? acc[o >> 1][3].y : acc[o >> 1][3].x;
    float s = g0 + g1 + g2 + g3;
    float q = g0 * g0 + g1 * g1 + g2 * g2 + g3 * g3;
#pragma unroll
    for (int off = 32; off > 0; off >>= 1) {
      s += __shfl_down(s, off, 64);
      q += __shfl_down(q, off, 64);
    }
    if (lane == 0) { s_red[0][wv][o] = s; s_red[1][wv][o] = q; }
  }
  __syncthreads();
  if (tid < 16) {
    float s = s_red[0][0][tid] + s_red[0][1][tid];
    float q = s_red[1][0][tid] + s_red[1][1][tid];
    long slot = (long)n * BSZ + b;
    p3[slot * 32 + tid] = s;
    p3[slot * 32 + 16 + tid] = q;
  }
}

// ---------------------------------------------------------------------------
// F3: BN3 + ReLU + avg over pooled raw conv3 -> feat[b][n][16].
// grid: (1, B, N), block 256 (16 chans x 16 threads).
// ---------------------------------------------------------------------------
__global__ __launch_bounds__(256) void feat_apply(
    const float* __restrict__ y3p,
    const float* __restrict__ scs3,
    float* __restrict__ feat) {
  int tid = threadIdx.x, n = blockIdx.z, b = blockIdx.y;
  int ch = tid >> 4, s = tid & 15;
  const float* yb = y3p + (((long)n * BSZ + b) * 16 + ch) * 250;
  float sc = scs3[n * 64 + ch], sh = scs3[n * 64 + 32 + ch];
  float acc = 0.f;
  for (int j = s; j < 125; j += 16) {
    float2 v = *(const float2*)&yb[2 * j];
    acc += fmaxf(v.x * sc + sh, 0.f) + fmaxf(v.y * sc + sh, 0.f);
  }
#pragma unroll
  for (int off = 8; off > 0; off >>= 1) acc += __shfl_down(acc, off, 16);
  if (s == 0) feat[((long)b * NND + n) * 16 + ch] = acc * (1.0f / 250.f);
}

// ---------------------------------------------------------------------------
// Graph tail: adjacency (top-4 incl self) + 3 GCN layers + node-mean + MLP
// grid: (B), block: 256.
// ---------------------------------------------------------------------------
__global__ __launch_bounds__(256) void graph_head(
    const float* __restrict__ feat,
    const float* __restrict__ gw1, const float* __restrict__ gb1,
    const float* __restrict__ gw2, const float* __restrict__ gb2,
    const float* __restrict__ gw3, const float* __restrict__ gb3,
    const float* __restrict__ fw1, const float* __restrict__ fb1,
    const float* __restrict__ fw2, const float* __restrict__ fb2,
    float* __restrict__ out) {
  int b = blockIdx.x, tid = threadIdx.x;
  __shared__ float s_feat[NND][16];
  __shared__ float s_sq[NND];
  __shared__ float s_dist[NND][NND];
  __shared__ float s_adj[NND][NND];
  __shared__ float s_x[NND][128];
  __shared__ float s_t[NND][128];
  __shared__ float s_pool[128];
  __shared__ float s_h[64];
  for (int i = tid; i < NND * 16; i += 256) s_feat[i >> 4][i & 15] = feat[b * NND * 16 + i];
  __syncthreads();
  if (tid < NND) {
    float s = 0.f;
    for (int c = 0; c < 16; c++) s += s_feat[tid][c] * s_feat[tid][c];
    s_sq[tid] = s;
  }
  __syncthreads();
  for (int i = tid; i < NND * NND; i += 256) {
    int nn = i / NND, m = i % NND;
    float d = 0.f;
    for (int c = 0; c < 16; c++) d += s_feat[nn][c] * s_feat[m][c];
    s_dist[nn][m] = s_sq[nn] + s_sq[m] - 2.f * d;  // diagonal exactly 0
    s_adj[nn][m] = 0.f;
  }
  __syncthreads();
  if (tid < NND) {  // top-4 smallest, ties -> earliest index (matches top_k)
    unsigned used = 0;
    for (int j = 0; j < 4; j++) {
      float best = 3.4e38f; int bi = 0;
      for (int m = 0; m < NND; m++)
        if (!((used >> m) & 1u) && s_dist[tid][m] < best) { best = s_dist[tid][m]; bi = m; }
      used |= 1u << bi;
      s_adj[tid][bi] = 0.25f;
    }
  }
  __syncthreads();
  for (int i = tid; i < NND * 32; i += 256) {
    int nn = i / 32, f = i % 32;
    float a = 0.f;
    for (int c = 0; c < 16; c++) a += s_feat[nn][c] * gw1[c * 32 + f];
    s_t[nn][f] = a;
  }
  __syncthreads();
  for (int i = tid; i < NND * 32; i += 256) {
    int nn = i / 32, f = i % 32;
    float a = gb1[f];
    for (int m = 0; m < NND; m++) a += s_adj[nn][m] * s_t[m][f];
    s_x[nn][f] = fmaxf(a, 0.f);
  }
  __syncthreads();
  for (int i = tid; i < NND * 64; i += 256) {
    int nn = i / 64, f = i % 64;
    float a = 0.f;
    for (int c = 0; c < 32; c++) a += s_x[nn][c] * gw2[c * 64 + f];
    s_t[nn][f] = a;
  }
  __syncthreads();
  for (int i = tid; i < NND * 64; i += 256) {
    int nn = i / 64, f = i % 64;
    float a = gb2[f];
    for (int m = 0; m < NND; m++) a += s_adj[nn][m] * s_t[m][f];
    s_x[nn][f] = fmaxf(a, 0.f);
  }
  __syncthreads();
  for (int i = tid; i < NND * 128; i += 256) {
    int nn = i / 128, f = i % 128;
    float a = 0.f;
    for (int c = 0; c < 64; c++) a += s_x[nn][c] * gw3[c * 128 + f];
    s_t[nn][f] = a;
  }
  __syncthreads();
  for (int i = tid; i < NND * 128; i += 256) {
    int nn = i / 128, f = i % 128;
    float a = gb3[f];
    for (int m = 0; m < NND; m++) a += s_adj[nn][m] * s_t[m][f];
    s_x[nn][f] = fmaxf(a, 0.f);
  }
  __syncthreads();
  if (tid < 128) {
    float a = 0.f;
    for (int m = 0; m < NND; m++) a += s_x[m][tid];
    s_pool[tid] = a * (1.0f / (float)NND);
  }
  __syncthreads();
  if (tid < 64) {
    float a = fb1[tid];
    for (int c = 0; c < 128; c++) a += s_pool[c] * fw1[c * 64 + tid];
    s_h[tid] = a;
  }
  __syncthreads();
  if (tid < 4) {
    float a = fb2[tid];
    for (int c = 0; c < 64; c++) a += s_h[c] * fw2[c * 4 + tid];
    out[b * 4 + tid] = a;
  }
}

extern "C" void kernel_launch(void* const* d_in, const int* in_sizes, int n_in,
                              void* d_out, int out_size, void* d_ws, size_t ws_size,
                              hipStream_t stream) {
  (void)in_sizes; (void)n_in; (void)out_size; (void)ws_size;
  const float* x   = (const float*)d_in[0];
  const float* w1  = (const float*)d_in[1];
  const float* g1  = (const float*)d_in[2];
  const float* b1  = (const float*)d_in[3];
  const float* w2  = (const float*)d_in[4];
  const float* g2  = (const float*)d_in[5];
  const float* b2  = (const float*)d_in[6];
  const float* w3  = (const float*)d_in[7];
  const float* g3  = (const float*)d_in[8];
  const float* b3  = (const float*)d_in[9];
  const float* gw1 = (const float*)d_in[10];
  const float* gb1 = (const float*)d_in[11];
  const float* gw2 = (const float*)d_in[12];
  const float* gb2 = (const float*)d_in[13];
  const float* gw3 = (const float*)d_in[14];
  const float* gb3 = (const float*)d_in[15];
  const float* fw1 = (const float*)d_in[16];
  const float* fb1 = (const float*)d_in[17];
  const float* fw2 = (const float*)d_in[18];
  const float* fb2 = (const float*)d_in[19];

  float* ws = (float*)d_ws;
  const long RSZ = (long)NND * BSZ * 4000;      // 22,528,000 floats per region
  float* y1p  = ws;                              // region A (reused as y3p)
  float* y3p  = ws;                              //   y1p dead before fused2 writes
  float* y2p  = ws + RSZ;                        // region B
  float* feat = y2p + RSZ;                       // B*N*16 = 90,112
  float* scs1 = feat + (long)BSZ * NND * 16;
  float* scs2 = scs1 + NND * 64;
  float* scs3 = scs2 + NND * 64;
  float* p1   = scs3 + NND * 64;                 // 22*512 slots * 8
  float* p2   = p1 + (long)NND * 512 * 8;        // 22*256 slots * 16
  float* p3   = p2 + (long)NND * 256 * 16;       // 22*256 slots * 32
  float* w2t  = p3 + (long)NND * 256 * 32;       // 224
  float* w3t  = w2t + 224;                       // 896
  // total ws ~= 181 MB (same budget as all prior passing rounds)

  // S1': conv1 stats + pooled raw conv1 -> y1p
  conv_stats1p<1, 4, 2000, 256, 2, 4><<<dim3(2, BSZ, NND), dim3(256), 0, stream>>>(
      x, 2000, (long)NND * 2000, 0, w1, p1, y1p);
  // reduce1 (+ weight pre-transpose in block 0)
  stats_reduce<4, 512, 2000><<<dim3(NND), dim3(256), 0, stream>>>(
      p1, g1, b1, scs1, w2, w3, w2t, w3t);
  // conv2 direct-from-global (BN1 in regs) -> y2p + stats2
  fused1<<<dim3(1, BSZ, NND), dim3(256), 0, stream>>>(y1p, scs1, w2t, y2p, p2);
  stats_reduce<8, 256, 1000><<<dim3(NND), dim3(256), 0, stream>>>(
      p2, g2, b2, scs2, nullptr, nullptr, nullptr, nullptr);
  // conv3 direct-from-global, 16 chan/thread -> y3p + stats3
  fused2<<<dim3(1, BSZ, NND), dim3(128), 0, stream>>>(y2p, scs2, w3t, y3p, p3);
  stats_reduce<16, 256, 500><<<dim3(NND), dim3(256), 0, stream>>>(
      p3, g3, b3, scs3, nullptr, nullptr, nullptr, nullptr);
  // BN3 + ReLU + avg -> feat
  feat_apply<<<dim3(1, BSZ, NND), dim3(256), 0, stream>>>(y3p, scs3, feat);
  // graph tail
  graph_head<<<dim3(BSZ), dim3(256), 0, stream>>>(
      feat, gw1, gb1, gw2, gb2, gw3, gb3, fw1, fb1, fw2, fb2, (float*)d_out);
}